// Round 2
// baseline (230.978 us; speedup 1.0000x reference)
//
#include <hip/hip_runtime.h>

// IDWT reconstruction layer, register p-tiled.
// x: (B=16, L=32768, 64) f32, channels [0,32)=approx, [32,64)=detail.
// out: (16, 2L=65536, 32) f32.
//
// out[b, 2p,   c] = sum_t lo[2t+1]*A[p-1+t] + hi[2t+1]*D[p-1+t]
// out[b, 2p+1, c] = sum_t lo[2t  ]*A[p-1+t] + hi[2t  ]*D[p-1+t]
// (t in 0..3; rows outside [0,L) contribute zero)
//
// Each thread handles PT=4 consecutive p for one 4-channel group:
// loads rows p0-1 .. p0+5 (7 rows) ONCE into registers instead of
// 4 threads x 4 rows = 16 row-loads. VMEM instr: 14 vs 32 per 4p.

#define B_    16
#define L_    32768
#define CIN_  64
#define COUT_ 32
#define PT    4
#define NROW  (PT + 3)   // 7

// native vector type for nontemporal builtins (HIP float4 is a struct)
typedef float vfloat4 __attribute__((ext_vector_type(4)));

__global__ __launch_bounds__(256) void idwt_kernel(
    const float* __restrict__ x,
    const float* __restrict__ rec_lo,
    const float* __restrict__ rec_hi,
    float* __restrict__ out)
{
    const int tid = blockIdx.x * blockDim.x + threadIdx.x;
    const int g  = tid & 7;                   // channel group of 4 (c = 4g)
    const int pp = tid >> 3;                  // (b, p0/PT) combined
    const int p0 = (pp & (L_ / PT - 1)) * PT;
    const int b  = pp >> 13;                  // L_/PT = 8192 = 2^13

    const float* xb = x + b * (L_ * CIN_) + (g << 2);

    // Stage 7 rows (A and D halves) in registers.
    float A[NROW][4], D[NROW][4];
#pragma unroll
    for (int r = 0; r < NROW; ++r) {
        const int j = p0 - 1 + r;
        if (j >= 0 && j < L_) {               // false only at batch edges
            const vfloat4 a = *(const vfloat4*)(xb + j * CIN_);
            const vfloat4 d = *(const vfloat4*)(xb + j * CIN_ + COUT_);
            A[r][0] = a.x; A[r][1] = a.y; A[r][2] = a.z; A[r][3] = a.w;
            D[r][0] = d.x; D[r][1] = d.y; D[r][2] = d.z; D[r][3] = d.w;
        } else {
#pragma unroll
            for (int c = 0; c < 4; ++c) { A[r][c] = 0.f; D[r][c] = 0.f; }
        }
    }

    // wave-uniform filter loads (compiler scalarizes to s_load)
    float lo[8], hi[8];
#pragma unroll
    for (int k = 0; k < 8; ++k) { lo[k] = rec_lo[k]; hi[k] = rec_hi[k]; }

    float* ob = out + (b * (2 * L_) + 2 * p0) * COUT_ + (g << 2);

#pragma unroll
    for (int pi = 0; pi < PT; ++pi) {
        float ev[4], od[4];
#pragma unroll
        for (int c = 0; c < 4; ++c) {
            float e = 0.f, o = 0.f;
#pragma unroll
            for (int t = 0; t < 4; ++t) {
                const float a = A[pi + t][c];
                const float d = D[pi + t][c];
                e = fmaf(lo[2 * t + 1], a, e);
                e = fmaf(hi[2 * t + 1], d, e);
                o = fmaf(lo[2 * t],     a, o);
                o = fmaf(hi[2 * t],     d, o);
            }
            ev[c] = e; od[c] = o;
        }
        // Output never re-read: nontemporal stores keep L2/LLC for input.
        vfloat4* pe = (vfloat4*)(ob + (2 * pi)     * COUT_);
        vfloat4* po = (vfloat4*)(ob + (2 * pi + 1) * COUT_);
        vfloat4 ve = { ev[0], ev[1], ev[2], ev[3] };
        vfloat4 vo = { od[0], od[1], od[2], od[3] };
        __builtin_nontemporal_store(ve, pe);
        __builtin_nontemporal_store(vo, po);
    }
}

extern "C" void kernel_launch(void* const* d_in, const int* in_sizes, int n_in,
                              void* d_out, int out_size, void* d_ws, size_t ws_size,
                              hipStream_t stream) {
    const float* x      = (const float*)d_in[0];
    const float* rec_lo = (const float*)d_in[1];
    const float* rec_hi = (const float*)d_in[2];
    float* out = (float*)d_out;

    const int total_threads = B_ * (L_ / PT) * (COUT_ / 4); // 16*8192*8 = 1,048,576
    const int block = 256;
    idwt_kernel<<<total_threads / block, block, 0, stream>>>(x, rec_lo, rec_hi, out);
}